// Round 10
// baseline (166.693 us; speedup 1.0000x reference)
//
#include <hip/hip_runtime.h>
#include <math.h>

// WaveletLayer: (B=4096, S=50, H=256) fp32.
// Per (b,h): 3-level db3 wavedec (ptwt reflect) -> per-band filter multiply ->
// waverec -> +residual -> LayerNorm over H.
// Round-9 = r8 + 2-batch-per-block software pipeline (T14 async-STAGE split):
//   grid 2048; block processes batches 2*blk, 2*blk+1. b1's 13 float4 loads
//   are ISSUED after b0's A'-writes (regs only; wavelet-pipeline regs are dead
//   by then) and written to LDS after b0's phase B drains -> b1's HBM latency
//   hides under b0's LN+stores, de-convoying the per-block phase structure.

#define S_LEN 50
#define H_DIM 256
#define NPAIR 25

typedef _Float16 f16;
typedef __attribute__((ext_vector_type(2))) _Float16 f16x2;
typedef __attribute__((ext_vector_type(4))) _Float16 f16x4;
typedef __attribute__((ext_vector_type(8))) _Float16 f16x8;

// d_ws layout (f16x2 elements): ft01 [10][256] | ft2 [8][256] | ft3 [14][256]
#define FT01_OFF 0
#define FT2_OFF (10 * H_DIM)
#define FT3_OFF (18 * H_DIM)
#define FT_BYTES (32 * H_DIM * 4)  // 32768

__device__ constexpr float DLO[6] = {
    0.035226291882100656f, -0.08544127388224149f, -0.13501102001039084f,
    0.4598775021193313f,   0.8068915093133388f,   0.3326705529509569f};
__device__ constexpr float DHI[6] = {
    -0.3326705529509569f,  0.8068915093133388f,  -0.4598775021193313f,
    -0.13501102001039084f, 0.08544127388224149f,  0.035226291882100656f};

static __device__ __forceinline__ f16x2 splat2(f16 v) {
  f16x2 r; r.x = v; r.y = v; return r;
}
static __device__ __forceinline__ f16x2 mk2(float a, float b) {
  f16x2 r; r.x = (f16)a; r.y = (f16)b; return r;
}

// Transpose+pack the learned filters into [l][h]-major f16x2 in ws.
__global__ void prep_filters(const float* __restrict__ f0,
                             const float* __restrict__ f1,
                             const float* __restrict__ f2,
                             const float* __restrict__ f3,
                             f16x2* __restrict__ ft) {
  const int h = threadIdx.x;
  const int b = blockIdx.x;
  if (b < 10) {  // (f0, f1) pair at tap l
    const int l = b;
    f16x2 v; v.x = (f16)f0[h * 10 + l]; v.y = (f16)f1[h * 10 + l];
    ft[FT01_OFF + l * H_DIM + h] = v;
  } else if (b < 18) {  // f2 taps (2k, 2k+1)
    const int k = b - 10;
    f16x2 v; v.x = (f16)f2[h * 16 + 2 * k]; v.y = (f16)f2[h * 16 + 2 * k + 1];
    ft[FT2_OFF + k * H_DIM + h] = v;
  } else {  // f3 taps (2k, 2k+1), last pair padded
    const int k = b - 18;
    f16x2 v;
    v.x = (f16)f3[h * 27 + 2 * k];
    v.y = (2 * k + 1 < 27) ? (f16)f3[h * 27 + 2 * k + 1] : (f16)0.f;
    ft[FT3_OFF + k * H_DIM + h] = v;
  }
}

// One analysis level, (lo,hi)-packed. out[i] = {cA[i], cD[i]}.
template <int N, class Get>
__device__ __forceinline__ void dwt_f16(const Get& X, f16x2* out) {
  constexpr int M = (N + 5) / 2;
#pragma unroll
  for (int i = 0; i < M; ++i) {
    f16x2 acc = mk2(0.f, 0.f);
#pragma unroll
    for (int j = 0; j < 6; ++j) {
      int idx = 2 * i + j - 4;
      idx = idx < 0 ? -idx : idx;
      idx = idx >= N ? 2 * N - 2 - idx : idx;
      acc += splat2(X(idx)) * mk2(DLO[5 - j], DHI[5 - j]);
    }
    out[i] = acc;
  }
}

// One synthesis level, adjacent-packed output: out2[t] = {rec[2t], rec[2t+1]}.
template <int T, class GLo, class GHi>
__device__ __forceinline__ void idwt_f16(const GLo& lo, const GHi& hi,
                                         f16x2* out2) {
#pragma unroll
  for (int t = 0; t < T / 2; ++t) {
    f16x2 acc = mk2(0.f, 0.f);
#pragma unroll
    for (int k = 0; k < 3; ++k) {
      acc += splat2(lo(t + k)) * mk2(DLO[2 * k + 1], DLO[2 * k]);
      acc += splat2(hi(t + k)) * mk2(DHI[2 * k + 1], DHI[2 * k]);
    }
    out2[t] = acc;
  }
  if constexpr (T & 1) {  // tail p = T-1 (even): taps {1,3,5}
    constexpr int t0 = T / 2;
    f16 s = (f16)0.f;
#pragma unroll
    for (int k = 0; k < 3; ++k)
      s += lo(t0 + k) * (f16)DLO[2 * k + 1] + hi(t0 + k) * (f16)DHI[2 * k + 1];
    f16x2 r; r.x = s; r.y = (f16)0.f;
    out2[t0] = r;
  }
}

template <bool USE_WS>
__global__ __launch_bounds__(256)
__attribute__((amdgpu_waves_per_eu(4, 8)))
void wavelet_ln_kernel(
    const float* __restrict__ in, const float* __restrict__ f0,
    const float* __restrict__ f1, const float* __restrict__ f2,
    const float* __restrict__ f3, const f16x2* __restrict__ ft,
    const float* __restrict__ gam, const float* __restrict__ bet,
    float* __restrict__ out) {
  __shared__ f16 slab[S_LEN * H_DIM];  // 25600 B -> up to 6 blocks/CU
  const int tid = threadIdx.x;
  const int h = tid;
  const int lane = tid & 63;
  const int wv = tid >> 6;
  const int half = lane >> 5;
  const int hq = lane & 31;

  const size_t base0 = (size_t)(2 * blockIdx.x) * (S_LEN * H_DIM);
  const size_t base1 = base0 + S_LEN * H_DIM;
  const float4* in4_0 = (const float4*)(in + base0);
  const float4* in4_1 = (const float4*)(in + base1);

  // LN constants (shared by both batches)
  const float4 ga = ((const float4*)gam)[hq];
  const float4 gb = ((const float4*)gam)[hq + 32];
  const float4 ba = ((const float4*)bet)[hq];
  const float4 bb = ((const float4*)bet)[hq + 32];

  float4 pa[7], pb[7];  // staging registers (x-pairs of one batch)

  // issue loads for a batch into pa/pb
  auto stage_regs = [&](const float4* in4) {
#pragma unroll
    for (int i = 0; i < 7; ++i) {
      const int idx = i * 256 + tid;  // quad-of-pairs index in [0,1600)
      if (idx < NPAIR * 64) {
        const int t = idx >> 6, q = idx & 63;
        pa[i] = in4[(2 * t) * 64 + q];
        pb[i] = in4[(2 * t + 1) * 64 + q];
      }
    }
  };
  // pack pa/pb -> pair-layout f16 slab
  auto write_slab = [&]() {
    f16x8* s8 = (f16x8*)slab;
#pragma unroll
    for (int i = 0; i < 7; ++i) {
      const int idx = i * 256 + tid;
      if (idx < NPAIR * 64) {
        f16x8 o;
        o.s0 = (f16)pa[i].x; o.s1 = (f16)pb[i].x;
        o.s2 = (f16)pa[i].y; o.s3 = (f16)pb[i].y;
        o.s4 = (f16)pa[i].z; o.s5 = (f16)pb[i].z;
        o.s6 = (f16)pa[i].w; o.s7 = (f16)pb[i].w;
        s8[idx] = o;
      }
    }
  };

  // full per-batch pipeline; if PREFETCH, issue next batch's loads after the
  // y-writes (wavelet registers dead there; live range spans only phase B)
  auto process = [&](float* __restrict__ outp, const float4* pf_in4,
                     bool prefetch) {
    // ---- phase A: pair reads -> packed fp16 wavelet pipeline ----
    f16x2 xp[NPAIR];
    const f16x2* sp = (const f16x2*)slab;
#pragma unroll
    for (int t = 0; t < NPAIR; ++t) xp[t] = sp[t * H_DIM + h];  // 2-way, free
    __syncthreads();  // slab re-written row-major below

    f16x2 AD1[27];
    dwt_f16<50>([&](int s) -> f16 { return (s & 1) ? xp[s >> 1].y
                                                   : xp[s >> 1].x; }, AD1);
    f16x2 AD2[16];
    dwt_f16<27>([&](int s) -> f16 { return AD1[s].x; }, AD2);
    f16x2 AD3[10];
    dwt_f16<16>([&](int s) -> f16 { return AD2[s].x; }, AD3);

    // per-band learned filter multiply
    if (USE_WS) {
#pragma unroll
      for (int l = 0; l < 10; ++l) AD3[l] *= ft[FT01_OFF + l * H_DIM + h];
#pragma unroll
      for (int k = 0; k < 8; ++k) {
        const f16x2 c = ft[FT2_OFF + k * H_DIM + h];
        AD2[2 * k].y *= c.x;
        AD2[2 * k + 1].y *= c.y;
      }
#pragma unroll
      for (int k = 0; k < 14; ++k) {
        const f16x2 c = ft[FT3_OFF + k * H_DIM + h];
        AD1[2 * k].y *= c.x;
        if (2 * k + 1 < 27) AD1[2 * k + 1].y *= c.y;
      }
    } else {
      const float* f0h = f0 + h * 10;
      const float* f1h = f1 + h * 10;
#pragma unroll
      for (int l = 0; l < 10; ++l) AD3[l] *= mk2(f0h[l], f1h[l]);
      const float* f2h = f2 + h * 16;
#pragma unroll
      for (int l = 0; l < 16; ++l) AD2[l].y *= (f16)f2h[l];
      const float* f3h = f3 + h * 27;
#pragma unroll
      for (int l = 0; l < 27; ++l) AD1[l].y *= (f16)f3h[l];
    }

    // synthesis
    f16x2 rr2[8];
    idwt_f16<16>([&](int s) -> f16 { return AD3[s].x; },
                 [&](int s) -> f16 { return AD3[s].y; }, rr2);
    f16x2 rr1[14];
    idwt_f16<27>([&](int s) -> f16 { return (s & 1) ? rr2[s >> 1].y
                                                    : rr2[s >> 1].x; },
                 [&](int s) -> f16 { return AD2[s].y; }, rr1);

    // final level fused with residual: slab <- y = x + rec, ROW-MAJOR
    auto lo = [&](int s) -> f16 { return (s & 1) ? rr1[s >> 1].y
                                                 : rr1[s >> 1].x; };
    auto hi = [&](int s) -> f16 { return AD1[s].y; };
#pragma unroll
    for (int t = 0; t < NPAIR; ++t) {
      f16x2 acc = mk2(0.f, 0.f);
#pragma unroll
      for (int k = 0; k < 3; ++k) {
        acc += splat2(lo(t + k)) * mk2(DLO[2 * k + 1], DLO[2 * k]);
        acc += splat2(hi(t + k)) * mk2(DHI[2 * k + 1], DHI[2 * k]);
      }
      const f16x2 y = xp[t] + acc;
      slab[(2 * t) * H_DIM + h] = y.x;
      slab[(2 * t + 1) * H_DIM + h] = y.y;
    }

    // ---- prefetch next batch (loads in flight across phase B) ----
    if (prefetch) stage_regs(pf_in4);
    __syncthreads();

    // ---- phase B: LN over H; one full row per 32-lane half-wave ----
    for (int p = wv; p < NPAIR; p += 4) {
      const int row = 2 * p + half;
      const f16x4 va = *(const f16x4*)&slab[row * H_DIM + hq * 4];
      const f16x4 vb = *(const f16x4*)&slab[row * H_DIM + 128 + hq * 4];
      const float y0 = (float)va.x, y1 = (float)va.y;
      const float y2 = (float)va.z, y3 = (float)va.w;
      const float y4 = (float)vb.x, y5 = (float)vb.y;
      const float y6 = (float)vb.z, y7 = (float)vb.w;
      float sum = ((y0 + y1) + (y2 + y3)) + ((y4 + y5) + (y6 + y7));
      float ssq = y0 * y0 + y1 * y1 + y2 * y2 + y3 * y3 +
                  y4 * y4 + y5 * y5 + y6 * y6 + y7 * y7;
#pragma unroll
      for (int o = 16; o >= 1; o >>= 1) {
        sum += __shfl_xor(sum, o);
        ssq += __shfl_xor(ssq, o);
      }
      const float mu = sum * (1.0f / H_DIM);
      const float var = fmaxf(ssq * (1.0f / H_DIM) - mu * mu, 0.0f);
      const float rs = rsqrtf(var + 1e-12f);
      float4 o1, o2;
      o1.x = (y0 - mu) * rs * ga.x + ba.x;
      o1.y = (y1 - mu) * rs * ga.y + ba.y;
      o1.z = (y2 - mu) * rs * ga.z + ba.z;
      o1.w = (y3 - mu) * rs * ga.w + ba.w;
      o2.x = (y4 - mu) * rs * gb.x + bb.x;
      o2.y = (y5 - mu) * rs * gb.y + bb.y;
      o2.z = (y6 - mu) * rs * gb.z + bb.z;
      o2.w = (y7 - mu) * rs * gb.w + bb.w;
      float4* row4 = (float4*)(outp + row * H_DIM);
      row4[hq] = o1;        // dense 512B per store instruction
      row4[hq + 32] = o2;
    }
  };

  // ---- batch 0 ----
  stage_regs(in4_0);
  write_slab();
  __syncthreads();
  process(out + base0, in4_1, true);   // prefetches batch 1 during phase B
  __syncthreads();                     // all B-reads of y(b0) done
  // ---- batch 1 (x already in pa/pb) ----
  write_slab();
  __syncthreads();
  process(out + base1, nullptr, false);
}

extern "C" void kernel_launch(void* const* d_in, const int* in_sizes, int n_in,
                              void* d_out, int out_size, void* d_ws,
                              size_t ws_size, hipStream_t stream) {
  // setup_inputs() dict order: input_tensor, ln_gamma, ln_beta, filt0..filt3
  const float* in = (const float*)d_in[0];
  const float* gam = (const float*)d_in[1];
  const float* bet = (const float*)d_in[2];
  const float* f0 = (const float*)d_in[3];
  const float* f1 = (const float*)d_in[4];
  const float* f2 = (const float*)d_in[5];
  const float* f3 = (const float*)d_in[6];
  float* out = (float*)d_out;

  if (ws_size >= (size_t)FT_BYTES) {
    f16x2* ft = (f16x2*)d_ws;
    prep_filters<<<32, 256, 0, stream>>>(f0, f1, f2, f3, ft);
    wavelet_ln_kernel<true><<<2048, 256, 0, stream>>>(in, f0, f1, f2, f3, ft,
                                                      gam, bet, out);
  } else {
    wavelet_ln_kernel<false><<<2048, 256, 0, stream>>>(
        in, f0, f1, f2, f3, nullptr, gam, bet, out);
  }
}

// Round 11
// 111.178 us; speedup vs baseline: 1.4993x; 1.4993x over previous
//
#include <hip/hip_runtime.h>
#include <math.h>

// WaveletLayer: (B=4096, S=50, H=256) fp32.
// Per (b,h): 3-level db3 wavedec (ptwt reflect) -> per-band filter multiply ->
// waverec -> +residual -> LayerNorm over H.
// Round-10 = r8 + register-BOUNDED 2-batch pipeline (r9 retry, spill-safe):
//   grid 2048, double-buffered LDS slab (2 x 25.6KB -> 3 blocks/CU).
//   b1's 13 load-chunks are a depth-1 rotating pipeline INSIDE b0's phase-B
//   loop: iter j issues chunk j (2 float4, 8 VGPR, live ONE iter), runs one
//   LN body, writes chunk j-1 to slab[1]. Fully unrolled -> static regs.
//   r9 failed holding 56 VGPR across the whole phase; this holds 16.

#define S_LEN 50
#define H_DIM 256
#define NPAIR 25

typedef _Float16 f16;
typedef __attribute__((ext_vector_type(2))) _Float16 f16x2;
typedef __attribute__((ext_vector_type(4))) _Float16 f16x4;
typedef __attribute__((ext_vector_type(8))) _Float16 f16x8;

// d_ws layout (f16x2 elements): ft01 [10][256] | ft2 [8][256] | ft3 [14][256]
#define FT01_OFF 0
#define FT2_OFF (10 * H_DIM)
#define FT3_OFF (18 * H_DIM)
#define FT_BYTES (32 * H_DIM * 4)  // 32768

__device__ constexpr float DLO[6] = {
    0.035226291882100656f, -0.08544127388224149f, -0.13501102001039084f,
    0.4598775021193313f,   0.8068915093133388f,   0.3326705529509569f};
__device__ constexpr float DHI[6] = {
    -0.3326705529509569f,  0.8068915093133388f,  -0.4598775021193313f,
    -0.13501102001039084f, 0.08544127388224149f,  0.035226291882100656f};

static __device__ __forceinline__ f16x2 splat2(f16 v) {
  f16x2 r; r.x = v; r.y = v; return r;
}
static __device__ __forceinline__ f16x2 mk2(float a, float b) {
  f16x2 r; r.x = (f16)a; r.y = (f16)b; return r;
}

// Transpose+pack the learned filters into [l][h]-major f16x2 in ws.
__global__ void prep_filters(const float* __restrict__ f0,
                             const float* __restrict__ f1,
                             const float* __restrict__ f2,
                             const float* __restrict__ f3,
                             f16x2* __restrict__ ft) {
  const int h = threadIdx.x;
  const int b = blockIdx.x;
  if (b < 10) {  // (f0, f1) pair at tap l
    const int l = b;
    f16x2 v; v.x = (f16)f0[h * 10 + l]; v.y = (f16)f1[h * 10 + l];
    ft[FT01_OFF + l * H_DIM + h] = v;
  } else if (b < 18) {  // f2 taps (2k, 2k+1)
    const int k = b - 10;
    f16x2 v; v.x = (f16)f2[h * 16 + 2 * k]; v.y = (f16)f2[h * 16 + 2 * k + 1];
    ft[FT2_OFF + k * H_DIM + h] = v;
  } else {  // f3 taps (2k, 2k+1), last pair padded
    const int k = b - 18;
    f16x2 v;
    v.x = (f16)f3[h * 27 + 2 * k];
    v.y = (2 * k + 1 < 27) ? (f16)f3[h * 27 + 2 * k + 1] : (f16)0.f;
    ft[FT3_OFF + k * H_DIM + h] = v;
  }
}

// One analysis level, (lo,hi)-packed. out[i] = {cA[i], cD[i]}.
template <int N, class Get>
__device__ __forceinline__ void dwt_f16(const Get& X, f16x2* out) {
  constexpr int M = (N + 5) / 2;
#pragma unroll
  for (int i = 0; i < M; ++i) {
    f16x2 acc = mk2(0.f, 0.f);
#pragma unroll
    for (int j = 0; j < 6; ++j) {
      int idx = 2 * i + j - 4;
      idx = idx < 0 ? -idx : idx;
      idx = idx >= N ? 2 * N - 2 - idx : idx;
      acc += splat2(X(idx)) * mk2(DLO[5 - j], DHI[5 - j]);
    }
    out[i] = acc;
  }
}

// One synthesis level, adjacent-packed output: out2[t] = {rec[2t], rec[2t+1]}.
template <int T, class GLo, class GHi>
__device__ __forceinline__ void idwt_f16(const GLo& lo, const GHi& hi,
                                         f16x2* out2) {
#pragma unroll
  for (int t = 0; t < T / 2; ++t) {
    f16x2 acc = mk2(0.f, 0.f);
#pragma unroll
    for (int k = 0; k < 3; ++k) {
      acc += splat2(lo(t + k)) * mk2(DLO[2 * k + 1], DLO[2 * k]);
      acc += splat2(hi(t + k)) * mk2(DHI[2 * k + 1], DHI[2 * k]);
    }
    out2[t] = acc;
  }
  if constexpr (T & 1) {  // tail p = T-1 (even): taps {1,3,5}
    constexpr int t0 = T / 2;
    f16 s = (f16)0.f;
#pragma unroll
    for (int k = 0; k < 3; ++k)
      s += lo(t0 + k) * (f16)DLO[2 * k + 1] + hi(t0 + k) * (f16)DHI[2 * k + 1];
    f16x2 r; r.x = s; r.y = (f16)0.f;
    out2[t0] = r;
  }
}

template <bool USE_WS>
__global__ __launch_bounds__(256)
__attribute__((amdgpu_waves_per_eu(3, 8)))
void wavelet_ln_kernel(
    const float* __restrict__ in, const float* __restrict__ f0,
    const float* __restrict__ f1, const float* __restrict__ f2,
    const float* __restrict__ f3, const f16x2* __restrict__ ft,
    const float* __restrict__ gam, const float* __restrict__ bet,
    float* __restrict__ out) {
  __shared__ f16 slab[2][S_LEN * H_DIM];  // 2 x 25600 B -> 3 blocks/CU
  const int tid = threadIdx.x;
  const int h = tid;
  const int lane = tid & 63;
  const int wv = tid >> 6;
  const int half = lane >> 5;
  const int hq = lane & 31;

  const size_t base0 = (size_t)(2 * blockIdx.x) * (S_LEN * H_DIM);
  const size_t base1 = base0 + S_LEN * H_DIM;
  const float4* in4_0 = (const float4*)(in + base0);
  const float4* in4_1 = (const float4*)(in + base1);

  // LN constants (shared by both batches)
  const float4 ga = ((const float4*)gam)[hq];
  const float4 gb = ((const float4*)gam)[hq + 32];
  const float4 ba = ((const float4*)bet)[hq];
  const float4 bb = ((const float4*)bet)[hq + 32];

  // ---- phases A+A' for one batch, on slab sl (pair layout -> y row-major) --
  auto wavelet = [&](f16* sl) {
    f16x2 xp[NPAIR];
    const f16x2* sp = (const f16x2*)sl;
#pragma unroll
    for (int t = 0; t < NPAIR; ++t) xp[t] = sp[t * H_DIM + h];  // 2-way, free
    __syncthreads();  // sl re-written row-major below

    f16x2 AD1[27];
    dwt_f16<50>([&](int s) -> f16 { return (s & 1) ? xp[s >> 1].y
                                                   : xp[s >> 1].x; }, AD1);
    f16x2 AD2[16];
    dwt_f16<27>([&](int s) -> f16 { return AD1[s].x; }, AD2);
    f16x2 AD3[10];
    dwt_f16<16>([&](int s) -> f16 { return AD2[s].x; }, AD3);

    if (USE_WS) {
#pragma unroll
      for (int l = 0; l < 10; ++l) AD3[l] *= ft[FT01_OFF + l * H_DIM + h];
#pragma unroll
      for (int k = 0; k < 8; ++k) {
        const f16x2 c = ft[FT2_OFF + k * H_DIM + h];
        AD2[2 * k].y *= c.x;
        AD2[2 * k + 1].y *= c.y;
      }
#pragma unroll
      for (int k = 0; k < 14; ++k) {
        const f16x2 c = ft[FT3_OFF + k * H_DIM + h];
        AD1[2 * k].y *= c.x;
        if (2 * k + 1 < 27) AD1[2 * k + 1].y *= c.y;
      }
    } else {
      const float* f0h = f0 + h * 10;
      const float* f1h = f1 + h * 10;
#pragma unroll
      for (int l = 0; l < 10; ++l) AD3[l] *= mk2(f0h[l], f1h[l]);
      const float* f2h = f2 + h * 16;
#pragma unroll
      for (int l = 0; l < 16; ++l) AD2[l].y *= (f16)f2h[l];
      const float* f3h = f3 + h * 27;
#pragma unroll
      for (int l = 0; l < 27; ++l) AD1[l].y *= (f16)f3h[l];
    }

    f16x2 rr2[8];
    idwt_f16<16>([&](int s) -> f16 { return AD3[s].x; },
                 [&](int s) -> f16 { return AD3[s].y; }, rr2);
    f16x2 rr1[14];
    idwt_f16<27>([&](int s) -> f16 { return (s & 1) ? rr2[s >> 1].y
                                                    : rr2[s >> 1].x; },
                 [&](int s) -> f16 { return AD2[s].y; }, rr1);

    auto lo = [&](int s) -> f16 { return (s & 1) ? rr1[s >> 1].y
                                                 : rr1[s >> 1].x; };
    auto hi = [&](int s) -> f16 { return AD1[s].y; };
#pragma unroll
    for (int t = 0; t < NPAIR; ++t) {
      f16x2 acc = mk2(0.f, 0.f);
#pragma unroll
      for (int k = 0; k < 3; ++k) {
        acc += splat2(lo(t + k)) * mk2(DLO[2 * k + 1], DLO[2 * k]);
        acc += splat2(hi(t + k)) * mk2(DHI[2 * k + 1], DHI[2 * k]);
      }
      const f16x2 y = xp[t] + acc;
      sl[(2 * t) * H_DIM + h] = y.x;   // own column only, 2-way free
      sl[(2 * t + 1) * H_DIM + h] = y.y;
    }
  };

  // one LN body: row-pair p of slab sl -> out rows
  auto ln_body = [&](const f16* sl, float* __restrict__ outp, int p) {
    const int row = 2 * p + half;
    const f16x4 va = *(const f16x4*)&sl[row * H_DIM + hq * 4];
    const f16x4 vb = *(const f16x4*)&sl[row * H_DIM + 128 + hq * 4];
    const float y0 = (float)va.x, y1 = (float)va.y;
    const float y2 = (float)va.z, y3 = (float)va.w;
    const float y4 = (float)vb.x, y5 = (float)vb.y;
    const float y6 = (float)vb.z, y7 = (float)vb.w;
    float sum = ((y0 + y1) + (y2 + y3)) + ((y4 + y5) + (y6 + y7));
    float ssq = y0 * y0 + y1 * y1 + y2 * y2 + y3 * y3 +
                y4 * y4 + y5 * y5 + y6 * y6 + y7 * y7;
#pragma unroll
    for (int o = 16; o >= 1; o >>= 1) {  // 5 levels within half-wave
      sum += __shfl_xor(sum, o);
      ssq += __shfl_xor(ssq, o);
    }
    const float mu = sum * (1.0f / H_DIM);
    const float var = fmaxf(ssq * (1.0f / H_DIM) - mu * mu, 0.0f);
    const float rs = rsqrtf(var + 1e-12f);
    float4 o1, o2;
    o1.x = (y0 - mu) * rs * ga.x + ba.x;
    o1.y = (y1 - mu) * rs * ga.y + ba.y;
    o1.z = (y2 - mu) * rs * ga.z + ba.z;
    o1.w = (y3 - mu) * rs * ga.w + ba.w;
    o2.x = (y4 - mu) * rs * gb.x + bb.x;
    o2.y = (y5 - mu) * rs * gb.y + bb.y;
    o2.z = (y6 - mu) * rs * gb.z + bb.z;
    o2.w = (y7 - mu) * rs * gb.w + bb.w;
    float4* row4 = (float4*)(outp + row * H_DIM);
    row4[hq] = o1;        // dense 512B per store instruction
    row4[hq + 32] = o2;
  };

  // ---- phase 0: stage batch 0 into slab[0] (pair layout, float4 loads) ----
  {
    f16x8* s8 = (f16x8*)slab[0];
#pragma unroll
    for (int i = 0; i < 7; ++i) {
      const int idx = i * 256 + tid;
      if (idx < NPAIR * 64) {
        const int t = idx >> 6, q = idx & 63;
        const float4 a = in4_0[(2 * t) * 64 + q];
        const float4 b = in4_0[(2 * t + 1) * 64 + q];
        f16x8 o;
        o.s0 = (f16)a.x; o.s1 = (f16)b.x;
        o.s2 = (f16)a.y; o.s3 = (f16)b.y;
        o.s4 = (f16)a.z; o.s5 = (f16)b.z;
        o.s6 = (f16)a.w; o.s7 = (f16)b.w;
        s8[idx] = o;
      }
    }
  }
  __syncthreads();

  // ---- batch 0 wavelet ----
  wavelet(slab[0]);
  __syncthreads();

  // ---- batch 0 LN + depth-1 rotating prefetch of batch 1 into slab[1] ----
  {
    f16x8* s8 = (f16x8*)slab[1];
    float4 fa[2], fb[2];  // one chunk in flight; static after full unroll
#pragma unroll
    for (int j = 0; j < 8; ++j) {
      // (1) issue chunk j's loads (live exactly one iteration)
      if (j < 7) {
        const int idx = j * 256 + tid;
        if (idx < NPAIR * 64) {
          const int t = idx >> 6, q = idx & 63;
          fa[j & 1] = in4_1[(2 * t) * 64 + q];
          fb[j & 1] = in4_1[(2 * t + 1) * 64 + q];
        }
      }
      // (2) one LN body (latency cover for chunk j's loads)
      if (j < 7) {
        const int p = wv + 4 * j;
        if (p < NPAIR) ln_body(slab[0], out + base0, p);
      }
      // (3) pack+write chunk j-1 (loads from last iteration have landed)
      if (j > 0) {
        const int idx = (j - 1) * 256 + tid;
        if (idx < NPAIR * 64) {
          const float4 a = fa[(j - 1) & 1];
          const float4 b = fb[(j - 1) & 1];
          f16x8 o;
          o.s0 = (f16)a.x; o.s1 = (f16)b.x;
          o.s2 = (f16)a.y; o.s3 = (f16)b.y;
          o.s4 = (f16)a.z; o.s5 = (f16)b.z;
          o.s6 = (f16)a.w; o.s7 = (f16)b.w;
          s8[idx] = o;
        }
      }
    }
  }
  __syncthreads();

  // ---- batch 1 wavelet + LN (plain) ----
  wavelet(slab[1]);
  __syncthreads();
  for (int p = wv; p < NPAIR; p += 4) ln_body(slab[1], out + base1, p);
}

extern "C" void kernel_launch(void* const* d_in, const int* in_sizes, int n_in,
                              void* d_out, int out_size, void* d_ws,
                              size_t ws_size, hipStream_t stream) {
  // setup_inputs() dict order: input_tensor, ln_gamma, ln_beta, filt0..filt3
  const float* in = (const float*)d_in[0];
  const float* gam = (const float*)d_in[1];
  const float* bet = (const float*)d_in[2];
  const float* f0 = (const float*)d_in[3];
  const float* f1 = (const float*)d_in[4];
  const float* f2 = (const float*)d_in[5];
  const float* f3 = (const float*)d_in[6];
  float* out = (float*)d_out;

  if (ws_size >= (size_t)FT_BYTES) {
    f16x2* ft = (f16x2*)d_ws;
    prep_filters<<<32, 256, 0, stream>>>(f0, f1, f2, f3, ft);
    wavelet_ln_kernel<true><<<2048, 256, 0, stream>>>(in, f0, f1, f2, f3, ft,
                                                      gam, bet, out);
  } else {
    wavelet_ln_kernel<false><<<2048, 256, 0, stream>>>(
        in, f0, f1, f2, f3, nullptr, gam, bet, out);
  }
}